// Round 14
// baseline (31.937 us; speedup 1.0000x reference)
//
#include <hip/hip_runtime.h>

// Reference collapses: softmax over singleton axis == 1 =>
//   out[b,c,:,:] = (Wout @ v_b + bout)[c],  v_b = Wkv[C:,:] @ context[b]
// x, Wq dead. Floor: 134 MB store @ ~7 TB/s (19 us) + K1 (1.5) + 2-node
// overhead (~6). In-kernel sync & 1-node variants all measured worse
// (R7 57us, R8 78us, R9 44us). R14: shave K1 dispatch ramp + K2 preamble
// exposure. If <=0.5us delta, declare roofline.

#define BB   16
#define CC   512
#define CTX  256
#define NN   4096   // H*W

typedef float f32x4 __attribute__((ext_vector_type(4)));

// K1: 512 blocks x 256 thr; wave = 4 consecutive (b,j) pairs (same b).
// 4 independent Wkv row loads (ILP), 4 dots, 4 butterflies.
__global__ __launch_bounds__(256) void v_kernel(
    const float* __restrict__ ctx,   // B x CTX
    const float* __restrict__ Wkv,   // 2C x CTX
    float* __restrict__ v)           // B*C (d_ws)
{
    const int w    = (blockIdx.x << 2) + (threadIdx.x >> 6);  // 0..2047
    const int lane = threadIdx.x & 63;
    const int j0   = w << 2;                // first of 4 consecutive rows
    const int b    = j0 >> 9;               // same batch for all 4

    const f32x4 cx = ((const f32x4*)(ctx + b * CTX))[lane];

    f32x4 wv[4];
    #pragma unroll
    for (int i = 0; i < 4; ++i)
        wv[i] = ((const f32x4*)(Wkv + (size_t)(CC + ((j0 + i) & (CC - 1))) * CTX))[lane];

    #pragma unroll
    for (int i = 0; i < 4; ++i) {
        float p = wv[i].x * cx.x + wv[i].y * cx.y + wv[i].z * cx.z + wv[i].w * cx.w;
        #pragma unroll
        for (int m = 32; m >= 1; m >>= 1) p += __shfl_xor(p, m);
        if (lane == 0) v[j0 + i] = p;
    }
}

// K2: 1024 blocks x 256 thr; block = (c, batch-half), wave = 2 batches.
// First store issues after ONE dot+butterfly; 4096 waves overlap preambles.
__global__ __launch_bounds__(256) void out_kernel(
    const float* __restrict__ v,     // B*C (32 KB, L2-hot)
    const float* __restrict__ Wout,  // C x C
    const float* __restrict__ bout,  // C
    f32x4* __restrict__ out)
{
    const int c    = blockIdx.x >> 1;            // 0..511
    const int half = blockIdx.x & 1;             // batches 0-7 or 8-15
    const int wave = threadIdx.x >> 6;           // 0..3
    const int lane = threadIdx.x & 63;
    const int b0   = (half << 3) + (wave << 1);  // 2 batches per wave

    const f32x4* wr = (const f32x4*)(Wout + (size_t)c * CC);
    const f32x4 w0 = wr[lane], w1 = wr[64 + lane];
    const float bb = bout[c];

    f32x4 v0[2], v1[2];
    #pragma unroll
    for (int i = 0; i < 2; ++i) {
        const f32x4* vr = (const f32x4*)(v + (size_t)(b0 + i) * CC);
        v0[i] = vr[lane];
        v1[i] = vr[64 + lane];
    }

    #pragma unroll
    for (int i = 0; i < 2; ++i) {
        float p = w0.x * v0[i].x + w0.y * v0[i].y + w0.z * v0[i].z + w0.w * v0[i].w
                + w1.x * v1[i].x + w1.y * v1[i].y + w1.z * v1[i].z + w1.w * v1[i].w;
        #pragma unroll
        for (int m = 32; m >= 1; m >>= 1) p += __shfl_xor(p, m);
        const float y = p + bb;

        f32x4 val; val.x = y; val.y = y; val.z = y; val.w = y;
        f32x4* dst = out + (size_t)(((b0 + i) << 9) + c) * (NN / 4) + lane;
        #pragma unroll
        for (int j = 0; j < 16; ++j)
            dst[j * 64] = val;
    }
}

extern "C" void kernel_launch(void* const* d_in, const int* in_sizes, int n_in,
                              void* d_out, int out_size, void* d_ws, size_t ws_size,
                              hipStream_t stream) {
    // inputs: 0=x (dead), 1=context, 2=Wq (dead), 3=Wkv, 4=Wout, 5=bout
    const float* context = (const float*)d_in[1];
    const float* Wkv     = (const float*)d_in[3];
    const float* Wout    = (const float*)d_in[4];
    const float* bout    = (const float*)d_in[5];
    f32x4* out = (f32x4*)d_out;
    float* v   = (float*)d_ws;   // 32 KB

    v_kernel<<<512, 256, 0, stream>>>(context, Wkv, v);
    out_kernel<<<1024, 256, 0, stream>>>(v, Wout, bout, out);
}

// Round 15
// 30.784 us; speedup vs baseline: 1.0374x; 1.0374x over previous
//
#include <hip/hip_runtime.h>

// Reference collapses: softmax over singleton axis == 1 =>
//   out[b,c,:,:] = (Wout @ v_b + bout)[c],  v_b = Wkv[C:,:] @ context[b]
// x, Wq dead. Bound by: 134 MB store (~19 us @ 7 TB/s) + ~3-4 us/graph-node.
// Measured-and-rejected: 1-kernel redundant (57.4), coop sync (77.7), soft
// barrier (44.4), fill-clone sweep (34.1), M-precompute (39.9), K2 wave
// reshapes (31.5-34.6). This (R13) is the best-measured structure: 30.75.

#define BB   16
#define CC   512
#define CTX  256
#define NN   4096   // H*W

typedef float f32x4 __attribute__((ext_vector_type(4)));

// K1: v[b*C+j] = dot(Wkv[C+j,:], ctx[b,:]).  One wave per (b,j).
__global__ __launch_bounds__(256) void v_kernel(
    const float* __restrict__ ctx,   // B x CTX
    const float* __restrict__ Wkv,   // 2C x CTX
    float* __restrict__ v)           // B*C (d_ws)
{
    const int w    = (blockIdx.x << 2) + (threadIdx.x >> 6);  // 0..8191
    const int lane = threadIdx.x & 63;
    const int b    = w >> 9;
    const int j    = w & (CC - 1);

    const f32x4 cx = ((const f32x4*)(ctx + b * CTX))[lane];
    const f32x4 wv = ((const f32x4*)(Wkv + (size_t)(CC + j) * CTX))[lane];
    float p = wv.x * cx.x + wv.y * cx.y + wv.z * cx.z + wv.w * cx.w;
    #pragma unroll
    for (int m = 32; m >= 1; m >>= 1) p += __shfl_xor(p, m);
    if (lane == 0) v[w] = p;
}

// K2: block = channel c (512 blocks, 4 waves); wave = 4 batches.
// Wout[c,:] read once per block (L1-deduped across its waves). All v rows
// hoisted (independent loads -> ILP), then per-batch {butterfly; 16 stores}
// so stores of batch i overlap the reduce of batch i+1.
__global__ __launch_bounds__(256) void out_kernel(
    const float* __restrict__ v,     // B*C (32 KB, L2-hot)
    const float* __restrict__ Wout,  // C x C
    const float* __restrict__ bout,  // C
    f32x4* __restrict__ out)
{
    const int c    = blockIdx.x;                 // 0..511
    const int wave = threadIdx.x >> 6;           // 0..3
    const int lane = threadIdx.x & 63;
    const int b0   = wave << 2;                  // 4 batches per wave

    const f32x4* wr = (const f32x4*)(Wout + (size_t)c * CC);
    const f32x4 w0 = wr[lane], w1 = wr[64 + lane];
    const float bb = bout[c];

    // hoist all v loads: 8 independent f32x4 (ILP hides L2 latency)
    f32x4 v0[4], v1[4];
    #pragma unroll
    for (int i = 0; i < 4; ++i) {
        const f32x4* vr = (const f32x4*)(v + (size_t)(b0 + i) * CC);
        v0[i] = vr[lane];
        v1[i] = vr[64 + lane];
    }

    #pragma unroll
    for (int i = 0; i < 4; ++i) {
        float p = w0.x * v0[i].x + w0.y * v0[i].y + w0.z * v0[i].z + w0.w * v0[i].w
                + w1.x * v1[i].x + w1.y * v1[i].y + w1.z * v1[i].z + w1.w * v1[i].w;
        #pragma unroll
        for (int m = 32; m >= 1; m >>= 1) p += __shfl_xor(p, m);
        const float y = p + bb;

        f32x4 val; val.x = y; val.y = y; val.z = y; val.w = y;
        f32x4* dst = out + (size_t)(((b0 + i) << 9) + c) * (NN / 4) + lane;
        #pragma unroll
        for (int j = 0; j < 16; ++j)
            dst[j * 64] = val;
    }
}

extern "C" void kernel_launch(void* const* d_in, const int* in_sizes, int n_in,
                              void* d_out, int out_size, void* d_ws, size_t ws_size,
                              hipStream_t stream) {
    // inputs: 0=x (dead), 1=context, 2=Wq (dead), 3=Wkv, 4=Wout, 5=bout
    const float* context = (const float*)d_in[1];
    const float* Wkv     = (const float*)d_in[3];
    const float* Wout    = (const float*)d_in[4];
    const float* bout    = (const float*)d_in[5];
    f32x4* out = (f32x4*)d_out;
    float* v   = (float*)d_ws;   // 32 KB

    v_kernel<<<2048, 256, 0, stream>>>(context, Wkv, v);
    out_kernel<<<512, 256, 0, stream>>>(v, Wout, bout, out);
}